// Round 3
// baseline (333.775 us; speedup 1.0000x reference)
//
#include <hip/hip_runtime.h>
#include <math.h>

#define N_NODES 5000
#define N_EDGES 50000

// ---------------- zero m + cnt in one pass ---------------------------------
__global__ void zero_kernel(int* __restrict__ p, int n) {
    int i = blockIdx.x * 256 + threadIdx.x;
    if (i < n) p[i] = 0;
}

// ---------------- t = relu(ef @ W1 + b1)  (E, 64) --------------------------
__global__ void edge_mlp1_kernel(const float* __restrict__ ef,
                                 const float* __restrict__ W1,
                                 const float* __restrict__ b1,
                                 float* __restrict__ t) {
    int gid = blockIdx.x * 256 + threadIdx.x;   // grid exact: 12500*256 = E*64
    int e = gid >> 6, i = gid & 63;             // e wave-uniform -> s_loads
    float acc = b1[i];
#pragma unroll
    for (int k = 0; k < 16; ++k)
        acc += ef[e * 16 + k] * W1[k * 64 + i];
    t[gid] = fmaxf(acc, 0.f);
}

// ---------------- V[n][k][i] = sum_j h[n,j] * W2[k, i*64+j] ----------------
// One wave per k-value; M[i=lane][j] (4096 floats) lives in 64 VGPRs.
// h[n] rows are wave-uniform -> s_load_dwordx4; inner loop = pure v_fmac.
__global__ __launch_bounds__(256) void vmat_kernel(const float* __restrict__ h,
                                                   const float* __restrict__ W2,
                                                   float* __restrict__ V) {
    int wave = threadIdx.x >> 6, lane = threadIdx.x & 63;
    int k = blockIdx.x * 4 + wave;              // grid.x = 16 -> k in 0..63
    int n0 = blockIdx.y * 50;                   // grid.y = 100 -> 5000 nodes
    float4 M[16];
    const float4* w4 = (const float4*)(W2 + (size_t)k * 4096 + lane * 64);
#pragma unroll
    for (int q = 0; q < 16; ++q) M[q] = w4[q];  // once per wave, L2-served
    float* Vk = V + (size_t)k * 64 + lane;
    for (int n = n0; n < n0 + 50; ++n) {
        const float4* hn = (const float4*)(h + (size_t)n * 64);
        float a0 = 0.f, a1 = 0.f, a2 = 0.f, a3 = 0.f;   // 4 chains: hide dep latency
#pragma unroll
        for (int q = 0; q < 16; ++q) {
            float4 hv = hn[q];                  // uniform -> s_load
            a0 += M[q].x * hv.x;
            a1 += M[q].y * hv.y;
            a2 += M[q].z * hv.z;
            a3 += M[q].w * hv.w;
        }
        Vk[(size_t)n * 4096] = (a0 + a1) + (a2 + a3);   // 256B coalesced store
    }
}

// ---------------- Wb[n][i] = sum_j h[n,j] * b2[i*64+j] ---------------------
__global__ void wb_kernel(const float* __restrict__ h,
                          const float* __restrict__ b2,
                          float* __restrict__ Wb) {
    int gid = blockIdx.x * 256 + threadIdx.x;   // exact: 1250*256 = N*64
    int n = gid >> 6, i = gid & 63;
    const float4* h4 = (const float4*)(h + n * 64);
    const float4* b24 = (const float4*)(b2 + i * 64);
    float acc = 0.f;
#pragma unroll
    for (int jb = 0; jb < 16; ++jb) {
        float4 hv = h4[jb], bv = b24[jb];
        acc += hv.x * bv.x + hv.y * bv.y + hv.z * bv.z + hv.w * bv.w;
    }
    Wb[gid] = acc;
}

// ---------------- counting sort of edges by src ----------------------------
__global__ void hist_kernel(const int* __restrict__ ei, int* __restrict__ cnt) {
    int e = blockIdx.x * 256 + threadIdx.x;
    if (e < N_EDGES) atomicAdd(&cnt[ei[e]], 1);
}

__global__ __launch_bounds__(1024) void scan_kernel(const int* __restrict__ cnt,
                                                    int* __restrict__ off,
                                                    int* __restrict__ cur) {
    __shared__ int s[1024];
    int tid = threadIdx.x;
    int base = tid * 5;                           // 1024*5 = 5120 >= 5000
    int loc[5]; int sum = 0;
#pragma unroll
    for (int q = 0; q < 5; ++q) {
        int v = (base + q < N_NODES) ? cnt[base + q] : 0;
        loc[q] = sum; sum += v;
    }
    s[tid] = sum; __syncthreads();
    for (int d = 1; d < 1024; d <<= 1) {
        int v = (tid >= d) ? s[tid - d] : 0;
        __syncthreads();
        s[tid] += v;
        __syncthreads();
    }
    int excl = (tid > 0) ? s[tid - 1] : 0;
#pragma unroll
    for (int q = 0; q < 5; ++q)
        if (base + q < N_NODES) { off[base + q] = excl + loc[q]; cur[base + q] = excl + loc[q]; }
    if (tid == 1023) off[N_NODES] = excl + sum;
}

__global__ void scatter_kernel(const int* __restrict__ ei,
                               int* __restrict__ cur, int* __restrict__ eperm) {
    int e = blockIdx.x * 256 + threadIdx.x;
    if (e < N_EDGES) {
        int p = atomicAdd(&cur[ei[e]], 1);
        eperm[p] = e;
    }
}

// ---------------- per-src messages: V[src] in 64 VGPRs, t via s_load -------
__global__ __launch_bounds__(256) void msg_kernel(const int* __restrict__ ei,
                                                  const int* __restrict__ off,
                                                  const int* __restrict__ eperm,
                                                  const float* __restrict__ t,
                                                  const float* __restrict__ V,
                                                  const float* __restrict__ Wb,
                                                  float* __restrict__ m) {
    int wave = threadIdx.x >> 6;
    int lane = threadIdx.x & 63;
    int n = blockIdx.x * 4 + wave;                // exact: 1250*4 = N
    int s0 = off[n], s1 = off[n + 1];
    if (s0 == s1) return;
    const float* Vn = V + (size_t)n * 4096;
    float vreg[64];
#pragma unroll
    for (int k = 0; k < 64; ++k) vreg[k] = Vn[k * 64 + lane];   // coalesced
    float wb = Wb[n * 64 + lane];
    for (int p = s0; p < s1; ++p) {
        int e = eperm[p];                         // uniform -> s_load
        int tgt = ei[N_EDGES + e];                // uniform -> s_load
        const float4* te = (const float4*)(t + (size_t)e * 64);
        float acc = wb;
#pragma unroll
        for (int q = 0; q < 16; ++q) {
            float4 tv = te[q];                    // uniform -> s_load (no DS ops!)
            acc += tv.x * vreg[q * 4 + 0] + tv.y * vreg[q * 4 + 1]
                 + tv.z * vreg[q * 4 + 2] + tv.w * vreg[q * 4 + 3];
        }
        atomicAdd(&m[tgt * 64 + lane], acc);
    }
}

// ---------------- transpose GRU weights: WT[j][row] ------------------------
__global__ void transpose_w_kernel(const float* __restrict__ Wih,
                                   const float* __restrict__ Whh,
                                   float* __restrict__ WihT,
                                   float* __restrict__ WhhT) {
    int idx = blockIdx.x * 256 + threadIdx.x;     // exact: 96*256 = 2*192*64
    int which = idx >= 12288;
    int tt = which ? idx - 12288 : idx;
    int row = tt >> 6, j = tt & 63;
    const float* src = which ? Whh : Wih;
    float* dst = which ? WhhT : WihT;
    dst[j * 192 + row] = src[tt];
}

// ---------------- GRU cell with coalesced (transposed) weights -------------
__global__ void gru_kernel(const float* __restrict__ m,
                           const float* __restrict__ h,
                           const float* __restrict__ WihT,
                           const float* __restrict__ WhhT,
                           const float* __restrict__ bih,
                           const float* __restrict__ bhh,
                           float* __restrict__ out) {
    int w = threadIdx.x >> 6, lane = threadIdx.x & 63;
    int n = blockIdx.x * 4 + w;                   // exact: 1250*4 = N
    int i = lane;
    float ir = bih[i], iz = bih[64 + i], inn = bih[128 + i];
    float hr = bhh[i], hz = bhh[64 + i], hn = bhh[128 + i];
    const float4* mn = (const float4*)(m + (size_t)n * 64);
    const float4* hnp = (const float4*)(h + (size_t)n * 64);
#pragma unroll 4
    for (int q = 0; q < 16; ++q) {
        float4 mv = mn[q];                        // uniform -> s_load
        float4 hv = hnp[q];
#pragma unroll
        for (int u = 0; u < 4; ++u) {
            int j = q * 4 + u;
            float mvx = u == 0 ? mv.x : u == 1 ? mv.y : u == 2 ? mv.z : mv.w;
            float hvx = u == 0 ? hv.x : u == 1 ? hv.y : u == 2 ? hv.z : hv.w;
            const float* wi = WihT + j * 192;     // lane-coalesced rows
            const float* wh = WhhT + j * 192;
            ir  += mvx * wi[i];
            iz  += mvx * wi[64 + i];
            inn += mvx * wi[128 + i];
            hr  += hvx * wh[i];
            hz  += hvx * wh[64 + i];
            hn  += hvx * wh[128 + i];
        }
    }
    float hval = h[(size_t)n * 64 + i];
    float r = 1.f / (1.f + expf(-(ir + hr)));
    float z = 1.f / (1.f + expf(-(iz + hz)));
    float nn = tanhf(inn + r * hn);
    out[n * 64 + i] = (1.f - z) * nn + z * hval;
}

extern "C" void kernel_launch(void* const* d_in, const int* in_sizes, int n_in,
                              void* d_out, int out_size, void* d_ws, size_t ws_size,
                              hipStream_t stream) {
    const float* h   = (const float*)d_in[0];
    const int*   ei  = (const int*)d_in[1];    // [2, E]: row0 = src, row1 = tgt
    const float* ef  = (const float*)d_in[2];
    const float* W1  = (const float*)d_in[3];
    const float* b1  = (const float*)d_in[4];
    const float* W2  = (const float*)d_in[5];
    const float* b2  = (const float*)d_in[6];
    const float* Wih = (const float*)d_in[7];
    const float* Whh = (const float*)d_in[8];
    const float* bih = (const float*)d_in[9];
    const float* bhh = (const float*)d_in[10];
    float* out = (float*)d_out;

    float* t    = (float*)d_ws;                        // E*64
    float* V    = t  + (size_t)N_EDGES * 64;           // N*4096
    float* Wb   = V  + (size_t)N_NODES * 4096;         // N*64
    float* m    = Wb + (size_t)N_NODES * 64;           // N*64
    int*   cnt  = (int*)(m + (size_t)N_NODES * 64);    // N (adjacent to m)
    int*   off  = cnt + N_NODES;                       // N+1
    int*   cur  = off + N_NODES + 1;                   // N
    int*   eperm= cur + N_NODES;                       // E
    float* WihT = (float*)(eperm + N_EDGES);           // 192*64
    float* WhhT = WihT + 192 * 64;                     // 192*64

    zero_kernel<<<(N_NODES * 64 + N_NODES + 255) / 256, 256, 0, stream>>>(
        (int*)m, N_NODES * 64 + N_NODES);
    edge_mlp1_kernel<<<12500, 256, 0, stream>>>(ef, W1, b1, t);
    vmat_kernel<<<dim3(16, 100), 256, 0, stream>>>(h, W2, V);
    wb_kernel<<<1250, 256, 0, stream>>>(h, b2, Wb);
    hist_kernel<<<(N_EDGES + 255) / 256, 256, 0, stream>>>(ei, cnt);
    scan_kernel<<<1, 1024, 0, stream>>>(cnt, off, cur);
    scatter_kernel<<<(N_EDGES + 255) / 256, 256, 0, stream>>>(ei, cur, eperm);
    msg_kernel<<<1250, 256, 0, stream>>>(ei, off, eperm, t, V, Wb, m);
    transpose_w_kernel<<<96, 256, 0, stream>>>(Wih, Whh, WihT, WhhT);
    gru_kernel<<<1250, 256, 0, stream>>>(m, h, WihT, WhhT, bih, bhh, out);
}

// Round 4
// 263.000 us; speedup vs baseline: 1.2691x; 1.2691x over previous
//
#include <hip/hip_runtime.h>
#include <math.h>

#define N_NODES 5000
#define N_EDGES 50000

// ---------------- zero m + cnt in one pass ---------------------------------
__global__ void zero_kernel(int* __restrict__ p, int n) {
    int i = blockIdx.x * 256 + threadIdx.x;
    if (i < n) p[i] = 0;
}

// ---------------- t = relu(ef @ W1 + b1)  (E, 64) --------------------------
__global__ void edge_mlp1_kernel(const float* __restrict__ ef,
                                 const float* __restrict__ W1,
                                 const float* __restrict__ b1,
                                 float* __restrict__ t) {
    int gid = blockIdx.x * 256 + threadIdx.x;   // grid exact: 12500*256 = E*64
    int e = gid >> 6, i = gid & 63;             // e wave-uniform -> s_loads
    float acc = b1[i];
#pragma unroll
    for (int k = 0; k < 16; ++k)
        acc += ef[e * 16 + k] * W1[k * 64 + i];
    t[gid] = fmaxf(acc, 0.f);
}

// ---------------- V[n][r] = sum_j h[n,j] * W2row[r][j],  r = k*64+i --------
// C(5000x4096) = A(5000x64) @ B^T, B = W2 as (4096x64) row-major.
// 128x128 tile, 8x8 per thread, ds_read_b128, stride 132 (16B-aligned pad).
__global__ __launch_bounds__(256) void vmat_kernel(const float* __restrict__ h,
                                                   const float* __restrict__ W2,
                                                   float* __restrict__ V) {
    __shared__ float hsT[64 * 132];   // [j][node_local]
    __shared__ float wsT[64 * 132];   // [j][row_local]
    int tid = threadIdx.x;
    int r0 = blockIdx.x * 128;        // B-row tile (4096/128 = 32, exact)
    int n0 = blockIdx.y * 128;        // node tile (ceil(5000/128) = 40)
#pragma unroll
    for (int it = 0; it < 32; ++it) {
        int idx = it * 256 + tid;     // 0..8191
        int row = idx >> 6, j = idx & 63;
        int n = n0 + row;
        hsT[j * 132 + row] = (n < N_NODES) ? h[(size_t)n * 64 + j] : 0.f;
        wsT[j * 132 + row] = W2[(size_t)(r0 + row) * 64 + j];
    }
    __syncthreads();
    int ty = tid >> 4, tx = tid & 15;   // ty: node group, tx: row group
    float acc[8][8] = {};
#pragma unroll 2
    for (int j = 0; j < 64; ++j) {
        float4 a0 = *(const float4*)&hsT[j * 132 + ty * 8];       // broadcast
        float4 a1 = *(const float4*)&hsT[j * 132 + ty * 8 + 4];
        float4 b0 = *(const float4*)&wsT[j * 132 + tx * 8];
        float4 b1 = *(const float4*)&wsT[j * 132 + tx * 8 + 4];
        float av[8] = {a0.x, a0.y, a0.z, a0.w, a1.x, a1.y, a1.z, a1.w};
        float bv[8] = {b0.x, b0.y, b0.z, b0.w, b1.x, b1.y, b1.z, b1.w};
#pragma unroll
        for (int a = 0; a < 8; ++a)
#pragma unroll
            for (int b = 0; b < 8; ++b)
                acc[a][b] += av[a] * bv[b];
    }
#pragma unroll
    for (int a = 0; a < 8; ++a) {
        int n = n0 + ty * 8 + a;
        if (n < N_NODES) {
            float4* dst = (float4*)(V + (size_t)n * 4096 + r0 + tx * 8);
            dst[0] = make_float4(acc[a][0], acc[a][1], acc[a][2], acc[a][3]);
            dst[1] = make_float4(acc[a][4], acc[a][5], acc[a][6], acc[a][7]);
        }
    }
}

// ---------------- Wb[n][i] = sum_j h[n,j] * b2[i*64+j] ---------------------
__global__ void wb_kernel(const float* __restrict__ h,
                          const float* __restrict__ b2,
                          float* __restrict__ Wb) {
    int gid = blockIdx.x * 256 + threadIdx.x;   // exact: 1250*256 = N*64
    int n = gid >> 6, i = gid & 63;
    const float4* h4 = (const float4*)(h + n * 64);
    const float4* b24 = (const float4*)(b2 + i * 64);
    float acc = 0.f;
#pragma unroll
    for (int jb = 0; jb < 16; ++jb) {
        float4 hv = h4[jb], bv = b24[jb];
        acc += hv.x * bv.x + hv.y * bv.y + hv.z * bv.z + hv.w * bv.w;
    }
    Wb[gid] = acc;
}

// ---------------- counting sort of edges by src ----------------------------
__global__ void hist_kernel(const int* __restrict__ ei, int* __restrict__ cnt) {
    int e = blockIdx.x * 256 + threadIdx.x;
    if (e < N_EDGES) atomicAdd(&cnt[ei[e]], 1);
}

__global__ __launch_bounds__(1024) void scan_kernel(const int* __restrict__ cnt,
                                                    int* __restrict__ off,
                                                    int* __restrict__ cur) {
    __shared__ int s[1024];
    int tid = threadIdx.x;
    int base = tid * 5;                           // 1024*5 = 5120 >= 5000
    int loc[5]; int sum = 0;
#pragma unroll
    for (int q = 0; q < 5; ++q) {
        int v = (base + q < N_NODES) ? cnt[base + q] : 0;
        loc[q] = sum; sum += v;
    }
    s[tid] = sum; __syncthreads();
    for (int d = 1; d < 1024; d <<= 1) {
        int v = (tid >= d) ? s[tid - d] : 0;
        __syncthreads();
        s[tid] += v;
        __syncthreads();
    }
    int excl = (tid > 0) ? s[tid - 1] : 0;
#pragma unroll
    for (int q = 0; q < 5; ++q)
        if (base + q < N_NODES) { off[base + q] = excl + loc[q]; cur[base + q] = excl + loc[q]; }
    if (tid == 1023) off[N_NODES] = excl + sum;
}

__global__ void scatter_kernel(const int* __restrict__ ei,
                               int* __restrict__ cur, int* __restrict__ eperm) {
    int e = blockIdx.x * 256 + threadIdx.x;
    if (e < N_EDGES) {
        int p = atomicAdd(&cur[ei[e]], 1);
        eperm[p] = e;
    }
}

// ---------------- per-src messages: V[src] in 64 VGPRs, t via s_load -------
__global__ __launch_bounds__(256) void msg_kernel(const int* __restrict__ ei,
                                                  const int* __restrict__ off,
                                                  const int* __restrict__ eperm,
                                                  const float* __restrict__ t,
                                                  const float* __restrict__ V,
                                                  const float* __restrict__ Wb,
                                                  float* __restrict__ m) {
    int wave = threadIdx.x >> 6;
    int lane = threadIdx.x & 63;
    int n = blockIdx.x * 4 + wave;                // exact: 1250*4 = N
    int s0 = off[n], s1 = off[n + 1];
    if (s0 == s1) return;
    const float* Vn = V + (size_t)n * 4096;
    float vreg[64];
#pragma unroll
    for (int k = 0; k < 64; ++k) vreg[k] = Vn[k * 64 + lane];   // coalesced
    float wb = Wb[n * 64 + lane];
    for (int p = s0; p < s1; ++p) {
        int e = eperm[p];                         // uniform -> s_load
        int tgt = ei[N_EDGES + e];                // uniform -> s_load
        const float4* te = (const float4*)(t + (size_t)e * 64);
        float acc = wb;
#pragma unroll
        for (int q = 0; q < 16; ++q) {
            float4 tv = te[q];                    // uniform -> s_load
            acc += tv.x * vreg[q * 4 + 0] + tv.y * vreg[q * 4 + 1]
                 + tv.z * vreg[q * 4 + 2] + tv.w * vreg[q * 4 + 3];
        }
        atomicAdd(&m[tgt * 64 + lane], acc);
    }
}

// ---------------- transpose GRU weights: WT[j][row] ------------------------
__global__ void transpose_w_kernel(const float* __restrict__ Wih,
                                   const float* __restrict__ Whh,
                                   float* __restrict__ WihT,
                                   float* __restrict__ WhhT) {
    int idx = blockIdx.x * 256 + threadIdx.x;     // exact: 96*256 = 2*192*64
    int which = idx >= 12288;
    int tt = which ? idx - 12288 : idx;
    int row = tt >> 6, j = tt & 63;
    const float* src = which ? Whh : Wih;
    float* dst = which ? WhhT : WihT;
    dst[j * 192 + row] = src[tt];
}

// ---------------- GRU cell with coalesced (transposed) weights -------------
__global__ void gru_kernel(const float* __restrict__ m,
                           const float* __restrict__ h,
                           const float* __restrict__ WihT,
                           const float* __restrict__ WhhT,
                           const float* __restrict__ bih,
                           const float* __restrict__ bhh,
                           float* __restrict__ out) {
    int w = threadIdx.x >> 6, lane = threadIdx.x & 63;
    int n = blockIdx.x * 4 + w;                   // exact: 1250*4 = N
    int i = lane;
    float ir = bih[i], iz = bih[64 + i], inn = bih[128 + i];
    float hr = bhh[i], hz = bhh[64 + i], hn = bhh[128 + i];
    const float4* mn = (const float4*)(m + (size_t)n * 64);
    const float4* hnp = (const float4*)(h + (size_t)n * 64);
#pragma unroll 4
    for (int q = 0; q < 16; ++q) {
        float4 mv = mn[q];                        // uniform -> s_load
        float4 hv = hnp[q];
#pragma unroll
        for (int u = 0; u < 4; ++u) {
            int j = q * 4 + u;
            float mvx = u == 0 ? mv.x : u == 1 ? mv.y : u == 2 ? mv.z : mv.w;
            float hvx = u == 0 ? hv.x : u == 1 ? hv.y : u == 2 ? hv.z : hv.w;
            const float* wi = WihT + j * 192;     // lane-coalesced rows
            const float* wh = WhhT + j * 192;
            ir  += mvx * wi[i];
            iz  += mvx * wi[64 + i];
            inn += mvx * wi[128 + i];
            hr  += hvx * wh[i];
            hz  += hvx * wh[64 + i];
            hn  += hvx * wh[128 + i];
        }
    }
    float hval = h[(size_t)n * 64 + i];
    float r = 1.f / (1.f + expf(-(ir + hr)));
    float z = 1.f / (1.f + expf(-(iz + hz)));
    float nn = tanhf(inn + r * hn);
    out[n * 64 + i] = (1.f - z) * nn + z * hval;
}

extern "C" void kernel_launch(void* const* d_in, const int* in_sizes, int n_in,
                              void* d_out, int out_size, void* d_ws, size_t ws_size,
                              hipStream_t stream) {
    const float* h   = (const float*)d_in[0];
    const int*   ei  = (const int*)d_in[1];    // [2, E]: row0 = src, row1 = tgt
    const float* ef  = (const float*)d_in[2];
    const float* W1  = (const float*)d_in[3];
    const float* b1  = (const float*)d_in[4];
    const float* W2  = (const float*)d_in[5];
    const float* b2  = (const float*)d_in[6];
    const float* Wih = (const float*)d_in[7];
    const float* Whh = (const float*)d_in[8];
    const float* bih = (const float*)d_in[9];
    const float* bhh = (const float*)d_in[10];
    float* out = (float*)d_out;

    float* t    = (float*)d_ws;                        // E*64
    float* V    = t  + (size_t)N_EDGES * 64;           // N*4096
    float* Wb   = V  + (size_t)N_NODES * 4096;         // N*64
    float* m    = Wb + (size_t)N_NODES * 64;           // N*64
    int*   cnt  = (int*)(m + (size_t)N_NODES * 64);    // N (adjacent to m)
    int*   off  = cnt + N_NODES;                       // N+1
    int*   cur  = off + N_NODES + 1;                   // N
    int*   eperm= cur + N_NODES;                       // E
    float* WihT = (float*)(eperm + N_EDGES);           // 192*64
    float* WhhT = WihT + 192 * 64;                     // 192*64

    zero_kernel<<<(N_NODES * 64 + N_NODES + 255) / 256, 256, 0, stream>>>(
        (int*)m, N_NODES * 64 + N_NODES);
    edge_mlp1_kernel<<<12500, 256, 0, stream>>>(ef, W1, b1, t);
    vmat_kernel<<<dim3(32, 40), 256, 0, stream>>>(h, W2, V);
    wb_kernel<<<1250, 256, 0, stream>>>(h, b2, Wb);
    hist_kernel<<<(N_EDGES + 255) / 256, 256, 0, stream>>>(ei, cnt);
    scan_kernel<<<1, 1024, 0, stream>>>(cnt, off, cur);
    scatter_kernel<<<(N_EDGES + 255) / 256, 256, 0, stream>>>(ei, cur, eperm);
    msg_kernel<<<1250, 256, 0, stream>>>(ei, off, eperm, t, V, Wb, m);
    transpose_w_kernel<<<96, 256, 0, stream>>>(Wih, Whh, WihT, WhhT);
    gru_kernel<<<1250, 256, 0, stream>>>(m, h, WihT, WhhT, bih, bhh, out);
}

// Round 5
// 214.335 us; speedup vs baseline: 1.5573x; 1.2271x over previous
//
#include <hip/hip_runtime.h>
#include <math.h>

#define N_NODES 5000
#define N_EDGES 50000
#define RDIM 4160                      // 4096 V-cols + 64 wb-cols

typedef __bf16 bf16x8 __attribute__((ext_vector_type(8)));
typedef float  f32x4  __attribute__((ext_vector_type(4)));

static __device__ __forceinline__ f32x4 mfma16(bf16x8 a, bf16x8 b, f32x4 c) {
    return __builtin_amdgcn_mfma_f32_16x16x32_bf16(a, b, c, 0, 0, 0);
}

// ---------------- prep: bf16 hi/lo converts + transposes + zeroing ---------
// segments: h(320000) | W2ext(266240) | WT(24576) | zero m(320000) | cnt(5000)
__global__ void prep_kernel(const float* __restrict__ h, const float* __restrict__ W2,
                            const float* __restrict__ b2,
                            const float* __restrict__ Wih, const float* __restrict__ Whh,
                            __bf16* __restrict__ hhi, __bf16* __restrict__ hlo,
                            __bf16* __restrict__ whi, __bf16* __restrict__ wlo,
                            float* __restrict__ WihT, float* __restrict__ WhhT,
                            float* __restrict__ m, int* __restrict__ cnt) {
    int g = blockIdx.x * 256 + threadIdx.x;
    if (g < 320000) {
        float x = h[g];
        __bf16 hi = (__bf16)x;
        hhi[g] = hi; hlo[g] = (__bf16)(x - (float)hi);
        return;
    }
    g -= 320000;
    if (g < 266240) {                     // W2 (262144) then b2 (4096) appended
        float x = (g < 262144) ? W2[g] : b2[g - 262144];
        __bf16 hi = (__bf16)x;
        whi[g] = hi; wlo[g] = (__bf16)(x - (float)hi);
        return;
    }
    g -= 266240;
    if (g < 24576) {                      // GRU weight transposes
        int which = g >= 12288;
        int tt = which ? g - 12288 : g;
        int row = tt >> 6, j = tt & 63;
        (which ? WhhT : WihT)[j * 192 + row] = (which ? Whh : Wih)[tt];
        return;
    }
    g -= 24576;
    if (g < 320000) { m[g] = 0.f; return; }
    g -= 320000;
    if (g < 5000) cnt[g] = 0;
}

// ---------------- V(5000 x 4160) = h(5000x64) @ W2ext^T via split-bf16 MFMA
// block = 4 waves, 32-node slab; wave handles 13 col-tiles of 16.
// grid = (157 slabs, 5 col-chunks of 832)
__global__ __launch_bounds__(256) void vmat_mfma(const __bf16* __restrict__ hhi,
                                                 const __bf16* __restrict__ hlo,
                                                 const __bf16* __restrict__ whi,
                                                 const __bf16* __restrict__ wlo,
                                                 float* __restrict__ V) {
    int tid = threadIdx.x;
    int wv = tid >> 6, lane = tid & 63;
    int lo16 = lane & 15, q16 = lane >> 4;
    int nbase = blockIdx.x * 32;
    int ct0 = blockIdx.y * 52 + wv * 13;         // first col-tile (of 260)
    bf16x8 ah[2][2], al[2][2];
#pragma unroll
    for (int mt = 0; mt < 2; ++mt) {
        int n = nbase + mt * 16 + lo16;
        if (n > N_NODES - 1) n = N_NODES - 1;    // pad rows; stores guarded
        const __bf16* ph = hhi + (size_t)n * 64 + q16 * 8;
        const __bf16* pl = hlo + (size_t)n * 64 + q16 * 8;
        ah[mt][0] = *(const bf16x8*)(ph);
        ah[mt][1] = *(const bf16x8*)(ph + 32);
        al[mt][0] = *(const bf16x8*)(pl);
        al[mt][1] = *(const bf16x8*)(pl + 32);
    }
    for (int q = 0; q < 13; ++q) {
        int r0 = (ct0 + q) * 16;
        const __bf16* pbh = whi + (size_t)(r0 + lo16) * 64 + q16 * 8;
        const __bf16* pbl = wlo + (size_t)(r0 + lo16) * 64 + q16 * 8;
        bf16x8 bh0 = *(const bf16x8*)(pbh);
        bf16x8 bh1 = *(const bf16x8*)(pbh + 32);
        bf16x8 bl0 = *(const bf16x8*)(pbl);
        bf16x8 bl1 = *(const bf16x8*)(pbl + 32);
#pragma unroll
        for (int mt = 0; mt < 2; ++mt) {
            f32x4 c = {0.f, 0.f, 0.f, 0.f};
            c = mfma16(ah[mt][0], bh0, c);       // hi*hi
            c = mfma16(ah[mt][1], bh1, c);
            c = mfma16(al[mt][0], bh0, c);       // lo*hi
            c = mfma16(al[mt][1], bh1, c);
            c = mfma16(ah[mt][0], bl0, c);       // hi*lo
            c = mfma16(ah[mt][1], bl1, c);
            int rowb = nbase + mt * 16 + q16 * 4;
            int col = r0 + lo16;
#pragma unroll
            for (int g = 0; g < 4; ++g) {        // D: col=lane&15, row=quad*4+g
                int n = rowb + g;
                if (n < N_NODES) V[(size_t)n * RDIM + col] = c[g];
            }
        }
    }
}

// ---------------- counting sort of edges by src ----------------------------
__global__ void hist_kernel(const int* __restrict__ ei, int* __restrict__ cnt) {
    int e = blockIdx.x * 256 + threadIdx.x;
    if (e < N_EDGES) atomicAdd(&cnt[ei[e]], 1);
}

__global__ __launch_bounds__(1024) void scan_kernel(const int* __restrict__ cnt,
                                                    int* __restrict__ off,
                                                    int* __restrict__ cur) {
    __shared__ int s[1024];
    int tid = threadIdx.x;
    int base = tid * 5;                           // 1024*5 = 5120 >= 5000
    int loc[5]; int sum = 0;
#pragma unroll
    for (int q = 0; q < 5; ++q) {
        int v = (base + q < N_NODES) ? cnt[base + q] : 0;
        loc[q] = sum; sum += v;
    }
    s[tid] = sum; __syncthreads();
    for (int d = 1; d < 1024; d <<= 1) {
        int v = (tid >= d) ? s[tid - d] : 0;
        __syncthreads();
        s[tid] += v;
        __syncthreads();
    }
    int excl = (tid > 0) ? s[tid - 1] : 0;
#pragma unroll
    for (int q = 0; q < 5; ++q)
        if (base + q < N_NODES) { off[base + q] = excl + loc[q]; cur[base + q] = excl + loc[q]; }
    if (tid == 1023) off[N_NODES] = excl + sum;
}

__global__ void scatter_kernel(const int* __restrict__ ei, int* __restrict__ cur,
                               int* __restrict__ eperm, int* __restrict__ tgtp) {
    int e = blockIdx.x * 256 + threadIdx.x;
    if (e < N_EDGES) {
        int p = atomicAdd(&cur[ei[e]], 1);
        eperm[p] = e;
        tgtp[p] = ei[N_EDGES + e];
    }
}

// ---------------- t[p] = relu(ef[eperm[p]] @ W1 + b1)  (permuted order) ----
__global__ void edge_mlp1_kernel(const int* __restrict__ eperm,
                                 const float* __restrict__ ef,
                                 const float* __restrict__ W1,
                                 const float* __restrict__ b1,
                                 float* __restrict__ t) {
    int gid = blockIdx.x * 256 + threadIdx.x;   // exact: 12500*256 = E*64
    int p = gid >> 6, i = gid & 63;             // p wave-uniform -> s_loads
    int e = eperm[p];
    float acc = b1[i];
#pragma unroll
    for (int k = 0; k < 16; ++k)
        acc += ef[e * 16 + k] * W1[k * 64 + i];
    t[gid] = fmaxf(acc, 0.f);
}

// ---------------- per-src messages: V[src] in 64 VGPRs, t streamed ---------
__global__ __launch_bounds__(256) void msg_kernel(const int* __restrict__ off,
                                                  const int* __restrict__ tgtp,
                                                  const float* __restrict__ t,
                                                  const float* __restrict__ V,
                                                  float* __restrict__ m) {
    int wave = threadIdx.x >> 6;
    int lane = threadIdx.x & 63;
    int n = blockIdx.x * 4 + wave;                // exact: 1250*4 = N
    int s0 = off[n], s1 = off[n + 1];
    if (s0 == s1) return;
    const float* Vn = V + (size_t)n * RDIM;
    float vreg[64];
#pragma unroll
    for (int k = 0; k < 64; ++k) vreg[k] = Vn[k * 64 + lane];   // coalesced
    float wb = Vn[4096 + lane];                   // folded b2 term
    for (int p = s0; p < s1; ++p) {
        int tgt = tgtp[p];                        // uniform, contiguous
        const float4* te = (const float4*)(t + (size_t)p * 64);
        float acc = wb;
#pragma unroll
        for (int q = 0; q < 16; ++q) {
            float4 tv = te[q];                    // uniform -> s_load, contiguous
            acc += tv.x * vreg[q * 4 + 0] + tv.y * vreg[q * 4 + 1]
                 + tv.z * vreg[q * 4 + 2] + tv.w * vreg[q * 4 + 3];
        }
        atomicAdd(&m[tgt * 64 + lane], acc);
    }
}

// ---------------- GRU cell with coalesced (transposed) weights -------------
__global__ void gru_kernel(const float* __restrict__ m,
                           const float* __restrict__ h,
                           const float* __restrict__ WihT,
                           const float* __restrict__ WhhT,
                           const float* __restrict__ bih,
                           const float* __restrict__ bhh,
                           float* __restrict__ out) {
    int w = threadIdx.x >> 6, lane = threadIdx.x & 63;
    int n = blockIdx.x * 4 + w;                   // exact: 1250*4 = N
    int i = lane;
    float ir = bih[i], iz = bih[64 + i], inn = bih[128 + i];
    float hr = bhh[i], hz = bhh[64 + i], hn = bhh[128 + i];
    const float4* mn = (const float4*)(m + (size_t)n * 64);
    const float4* hnp = (const float4*)(h + (size_t)n * 64);
#pragma unroll 4
    for (int q = 0; q < 16; ++q) {
        float4 mv = mn[q];                        // uniform -> s_load
        float4 hv = hnp[q];
#pragma unroll
        for (int u = 0; u < 4; ++u) {
            int j = q * 4 + u;
            float mvx = u == 0 ? mv.x : u == 1 ? mv.y : u == 2 ? mv.z : mv.w;
            float hvx = u == 0 ? hv.x : u == 1 ? hv.y : u == 2 ? hv.z : hv.w;
            const float* wi = WihT + j * 192;     // lane-coalesced rows
            const float* wh = WhhT + j * 192;
            ir  += mvx * wi[i];
            iz  += mvx * wi[64 + i];
            inn += mvx * wi[128 + i];
            hr  += hvx * wh[i];
            hz  += hvx * wh[64 + i];
            hn  += hvx * wh[128 + i];
        }
    }
    float hval = h[(size_t)n * 64 + i];
    float r = 1.f / (1.f + expf(-(ir + hr)));
    float z = 1.f / (1.f + expf(-(iz + hz)));
    float nn = tanhf(inn + r * hn);
    out[n * 64 + i] = (1.f - z) * nn + z * hval;
}

extern "C" void kernel_launch(void* const* d_in, const int* in_sizes, int n_in,
                              void* d_out, int out_size, void* d_ws, size_t ws_size,
                              hipStream_t stream) {
    const float* h   = (const float*)d_in[0];
    const int*   ei  = (const int*)d_in[1];    // [2, E]: row0 = src, row1 = tgt
    const float* ef  = (const float*)d_in[2];
    const float* W1  = (const float*)d_in[3];
    const float* b1  = (const float*)d_in[4];
    const float* W2  = (const float*)d_in[5];
    const float* b2  = (const float*)d_in[6];
    const float* Wih = (const float*)d_in[7];
    const float* Whh = (const float*)d_in[8];
    const float* bih = (const float*)d_in[9];
    const float* bhh = (const float*)d_in[10];
    float* out = (float*)d_out;

    // ws layout (floats). bf16 staging arrays OVERLAY the t region: they are
    // consumed by vmat_mfma, and t is written only afterwards (stream order).
    float* t    = (float*)d_ws;                        // 3,200,000 floats
    float* V    = t + 3200000;                         // 5000*4160
    float* m    = V + (size_t)N_NODES * RDIM;          // 320,000
    int*   cnt  = (int*)(m + 320000);                  // 5000
    int*   off  = cnt + N_NODES;                       // 5001
    int*   cur  = off + N_NODES + 1;                   // 5000
    int*   eperm= cur + N_NODES;                       // 50000
    int*   tgtp = eperm + N_EDGES;                     // 50000
    float* WihT = (float*)(tgtp + N_EDGES);            // 12288
    float* WhhT = WihT + 12288;                        // 12288
    __bf16* hhi = (__bf16*)d_ws;                       // 320000 (overlay)
    __bf16* hlo = hhi + 320000;                        // 320000
    __bf16* whi = hlo + 320000;                        // 266240
    __bf16* wlo = whi + 266240;                        // 266240 (< t's 12.8 MB)

    prep_kernel<<<3656, 256, 0, stream>>>(h, W2, b2, Wih, Whh,
                                          hhi, hlo, whi, wlo, WihT, WhhT, m, cnt);
    vmat_mfma<<<dim3(157, 5), 256, 0, stream>>>(hhi, hlo, whi, wlo, V);
    hist_kernel<<<(N_EDGES + 255) / 256, 256, 0, stream>>>(ei, cnt);
    scan_kernel<<<1, 1024, 0, stream>>>(cnt, off, cur);
    scatter_kernel<<<(N_EDGES + 255) / 256, 256, 0, stream>>>(ei, cur, eperm, tgtp);
    edge_mlp1_kernel<<<12500, 256, 0, stream>>>(eperm, ef, W1, b1, t);
    msg_kernel<<<1250, 256, 0, stream>>>(off, tgtp, t, V, m);
    gru_kernel<<<1250, 256, 0, stream>>>(m, h, WihT, WhhT, bih, bhh, out);
}

// Round 6
// 210.222 us; speedup vs baseline: 1.5877x; 1.0196x over previous
//
#include <hip/hip_runtime.h>
#include <math.h>

#define N_NODES 5000
#define N_EDGES 50000
#define RDIM 4160                      // 4096 V-cols + 64 wb-cols

typedef __bf16 bf16x8 __attribute__((ext_vector_type(8)));
typedef float  f32x4  __attribute__((ext_vector_type(4)));

static __device__ __forceinline__ f32x4 mfma16(bf16x8 a, bf16x8 b, f32x4 c) {
    return __builtin_amdgcn_mfma_f32_16x16x32_bf16(a, b, c, 0, 0, 0);
}

// ---------------- prep: bf16 hi/lo converts + transposes + zeroing ---------
// segments: h(320000) | W2ext(266240) | WT(24576) | zero m(320000) | cnt(5000)
__global__ void prep_kernel(const float* __restrict__ h, const float* __restrict__ W2,
                            const float* __restrict__ b2,
                            const float* __restrict__ Wih, const float* __restrict__ Whh,
                            __bf16* __restrict__ hhi, __bf16* __restrict__ hlo,
                            __bf16* __restrict__ whi, __bf16* __restrict__ wlo,
                            float* __restrict__ WihT, float* __restrict__ WhhT,
                            float* __restrict__ m, int* __restrict__ cnt) {
    int g = blockIdx.x * 256 + threadIdx.x;
    if (g < 320000) {
        float x = h[g];
        __bf16 hi = (__bf16)x;
        hhi[g] = hi; hlo[g] = (__bf16)(x - (float)hi);
        return;
    }
    g -= 320000;
    if (g < 266240) {                     // W2 (262144) then b2 (4096) appended
        float x = (g < 262144) ? W2[g] : b2[g - 262144];
        __bf16 hi = (__bf16)x;
        whi[g] = hi; wlo[g] = (__bf16)(x - (float)hi);
        return;
    }
    g -= 266240;
    if (g < 24576) {                      // GRU weight transposes
        int which = g >= 12288;
        int tt = which ? g - 12288 : g;
        int row = tt >> 6, j = tt & 63;
        (which ? WhhT : WihT)[j * 192 + row] = (which ? Whh : Wih)[tt];
        return;
    }
    g -= 24576;
    if (g < 320000) { m[g] = 0.f; return; }
    g -= 320000;
    if (g < 5000) cnt[g] = 0;
}

// ---------------- V(5000 x 4160) = h(5000x64) @ W2ext^T via split-bf16 MFMA
__global__ __launch_bounds__(256) void vmat_mfma(const __bf16* __restrict__ hhi,
                                                 const __bf16* __restrict__ hlo,
                                                 const __bf16* __restrict__ whi,
                                                 const __bf16* __restrict__ wlo,
                                                 float* __restrict__ V) {
    int tid = threadIdx.x;
    int wv = tid >> 6, lane = tid & 63;
    int lo16 = lane & 15, q16 = lane >> 4;
    int nbase = blockIdx.x * 32;
    int ct0 = blockIdx.y * 52 + wv * 13;         // first col-tile (of 260)
    bf16x8 ah[2][2], al[2][2];
#pragma unroll
    for (int mt = 0; mt < 2; ++mt) {
        int n = nbase + mt * 16 + lo16;
        if (n > N_NODES - 1) n = N_NODES - 1;    // pad rows; stores guarded
        const __bf16* ph = hhi + (size_t)n * 64 + q16 * 8;
        const __bf16* pl = hlo + (size_t)n * 64 + q16 * 8;
        ah[mt][0] = *(const bf16x8*)(ph);
        ah[mt][1] = *(const bf16x8*)(ph + 32);
        al[mt][0] = *(const bf16x8*)(pl);
        al[mt][1] = *(const bf16x8*)(pl + 32);
    }
    for (int q = 0; q < 13; ++q) {
        int r0 = (ct0 + q) * 16;
        const __bf16* pbh = whi + (size_t)(r0 + lo16) * 64 + q16 * 8;
        const __bf16* pbl = wlo + (size_t)(r0 + lo16) * 64 + q16 * 8;
        bf16x8 bh0 = *(const bf16x8*)(pbh);
        bf16x8 bh1 = *(const bf16x8*)(pbh + 32);
        bf16x8 bl0 = *(const bf16x8*)(pbl);
        bf16x8 bl1 = *(const bf16x8*)(pbl + 32);
#pragma unroll
        for (int mt = 0; mt < 2; ++mt) {
            f32x4 c = {0.f, 0.f, 0.f, 0.f};
            c = mfma16(ah[mt][0], bh0, c);       // hi*hi
            c = mfma16(ah[mt][1], bh1, c);
            c = mfma16(al[mt][0], bh0, c);       // lo*hi
            c = mfma16(al[mt][1], bh1, c);
            c = mfma16(ah[mt][0], bl0, c);       // hi*lo
            c = mfma16(ah[mt][1], bl1, c);
            int rowb = nbase + mt * 16 + q16 * 4;
            int col = r0 + lo16;
#pragma unroll
            for (int g = 0; g < 4; ++g) {        // D: col=lane&15, row=quad*4+g
                int n = rowb + g;
                if (n < N_NODES) V[(size_t)n * RDIM + col] = c[g];
            }
        }
    }
}

// ---------------- counting sort of edges by src ----------------------------
__global__ void hist_kernel(const int* __restrict__ ei, int* __restrict__ cnt) {
    int e = blockIdx.x * 256 + threadIdx.x;
    if (e < N_EDGES) atomicAdd(&cnt[ei[e]], 1);
}

__global__ __launch_bounds__(1024) void scan_kernel(const int* __restrict__ cnt,
                                                    int* __restrict__ off,
                                                    int* __restrict__ cur) {
    __shared__ int s[1024];
    int tid = threadIdx.x;
    int base = tid * 5;                           // 1024*5 = 5120 >= 5000
    int loc[5]; int sum = 0;
#pragma unroll
    for (int q = 0; q < 5; ++q) {
        int v = (base + q < N_NODES) ? cnt[base + q] : 0;
        loc[q] = sum; sum += v;
    }
    s[tid] = sum; __syncthreads();
    for (int d = 1; d < 1024; d <<= 1) {
        int v = (tid >= d) ? s[tid - d] : 0;
        __syncthreads();
        s[tid] += v;
        __syncthreads();
    }
    int excl = (tid > 0) ? s[tid - 1] : 0;
#pragma unroll
    for (int q = 0; q < 5; ++q)
        if (base + q < N_NODES) { off[base + q] = excl + loc[q]; cur[base + q] = excl + loc[q]; }
    if (tid == 1023) off[N_NODES] = excl + sum;
}

__global__ void scatter_kernel(const int* __restrict__ ei, int* __restrict__ cur,
                               int* __restrict__ eperm, int* __restrict__ tgtp) {
    int e = blockIdx.x * 256 + threadIdx.x;
    if (e < N_EDGES) {
        int p = atomicAdd(&cur[ei[e]], 1);
        eperm[p] = e;
        tgtp[p] = ei[N_EDGES + e];
    }
}

// ---------------- t[p] = relu(ef[eperm[p]] @ W1 + b1)  (permuted order) ----
__global__ void edge_mlp1_kernel(const int* __restrict__ eperm,
                                 const float* __restrict__ ef,
                                 const float* __restrict__ W1,
                                 const float* __restrict__ b1,
                                 float* __restrict__ t) {
    int gid = blockIdx.x * 256 + threadIdx.x;   // exact: 12500*256 = E*64
    int p = gid >> 6, i = gid & 63;             // p wave-uniform -> s_loads
    int e = eperm[p];
    float acc = b1[i];
#pragma unroll
    for (int k = 0; k < 16; ++k)
        acc += ef[e * 16 + k] * W1[k * 64 + i];
    t[gid] = fmaxf(acc, 0.f);
}

// ---------------- per-src messages, 2-way k-split + edge-unroll x2 ---------
// slot = node*2 + khalf; wave holds V[n][kh*32..kh*32+31][lane] in 32 VGPRs.
__global__ __launch_bounds__(256) void msg_kernel(const int* __restrict__ off,
                                                  const int* __restrict__ tgtp,
                                                  const float* __restrict__ t,
                                                  const float* __restrict__ V,
                                                  float* __restrict__ m) {
    int wave = threadIdx.x >> 6;
    int lane = threadIdx.x & 63;
    int slot = blockIdx.x * 4 + wave;             // exact: 2500*4 = 2*N
    int n = slot >> 1;
    int kh = (slot & 1) * 32;                     // k-half base
    int s0 = off[n], s1 = off[n + 1];
    if (s0 == s1) return;
    const float* Vn = V + (size_t)n * RDIM + (size_t)kh * 64;
    float vreg[32];
#pragma unroll
    for (int k = 0; k < 32; ++k) vreg[k] = Vn[k * 64 + lane];   // coalesced
    float wb = (kh == 0) ? V[(size_t)n * RDIM + 4096 + lane] : 0.f;
    int p = s0;
    for (; p + 1 < s1; p += 2) {
        int tgt0 = tgtp[p], tgt1 = tgtp[p + 1];   // uniform -> s_load
        const float4* te0 = (const float4*)(t + (size_t)p * 64 + kh);
        const float4* te1 = (const float4*)(t + (size_t)(p + 1) * 64 + kh);
        float acc0 = wb, acc1 = wb;
#pragma unroll
        for (int q = 0; q < 8; ++q) {
            float4 tv0 = te0[q];                  // uniform -> s_load
            float4 tv1 = te1[q];
            acc0 += tv0.x * vreg[q * 4 + 0] + tv0.y * vreg[q * 4 + 1]
                  + tv0.z * vreg[q * 4 + 2] + tv0.w * vreg[q * 4 + 3];
            acc1 += tv1.x * vreg[q * 4 + 0] + tv1.y * vreg[q * 4 + 1]
                  + tv1.z * vreg[q * 4 + 2] + tv1.w * vreg[q * 4 + 3];
        }
        atomicAdd(&m[tgt0 * 64 + lane], acc0);
        atomicAdd(&m[tgt1 * 64 + lane], acc1);
    }
    if (p < s1) {
        int tgt = tgtp[p];
        const float4* te = (const float4*)(t + (size_t)p * 64 + kh);
        float acc = wb;
#pragma unroll
        for (int q = 0; q < 8; ++q) {
            float4 tv = te[q];
            acc += tv.x * vreg[q * 4 + 0] + tv.y * vreg[q * 4 + 1]
                 + tv.z * vreg[q * 4 + 2] + tv.w * vreg[q * 4 + 3];
        }
        atomicAdd(&m[tgt * 64 + lane], acc);
    }
}

// ---------------- GRU cell with coalesced (transposed) weights -------------
__global__ void gru_kernel(const float* __restrict__ m,
                           const float* __restrict__ h,
                           const float* __restrict__ WihT,
                           const float* __restrict__ WhhT,
                           const float* __restrict__ bih,
                           const float* __restrict__ bhh,
                           float* __restrict__ out) {
    int w = threadIdx.x >> 6, lane = threadIdx.x & 63;
    int n = blockIdx.x * 4 + w;                   // exact: 1250*4 = N
    int i = lane;
    float ir = bih[i], iz = bih[64 + i], inn = bih[128 + i];
    float hr = bhh[i], hz = bhh[64 + i], hn = bhh[128 + i];
    const float4* mn = (const float4*)(m + (size_t)n * 64);
    const float4* hnp = (const float4*)(h + (size_t)n * 64);
#pragma unroll 4
    for (int q = 0; q < 16; ++q) {
        float4 mv = mn[q];                        // uniform -> s_load
        float4 hv = hnp[q];
#pragma unroll
        for (int u = 0; u < 4; ++u) {
            int j = q * 4 + u;
            float mvx = u == 0 ? mv.x : u == 1 ? mv.y : u == 2 ? mv.z : mv.w;
            float hvx = u == 0 ? hv.x : u == 1 ? hv.y : u == 2 ? hv.z : hv.w;
            const float* wi = WihT + j * 192;     // lane-coalesced rows
            const float* wh = WhhT + j * 192;
            ir  += mvx * wi[i];
            iz  += mvx * wi[64 + i];
            inn += mvx * wi[128 + i];
            hr  += hvx * wh[i];
            hz  += hvx * wh[64 + i];
            hn  += hvx * wh[128 + i];
        }
    }
    float hval = h[(size_t)n * 64 + i];
    float r = 1.f / (1.f + expf(-(ir + hr)));
    float z = 1.f / (1.f + expf(-(iz + hz)));
    float nn = tanhf(inn + r * hn);
    out[n * 64 + i] = (1.f - z) * nn + z * hval;
}

extern "C" void kernel_launch(void* const* d_in, const int* in_sizes, int n_in,
                              void* d_out, int out_size, void* d_ws, size_t ws_size,
                              hipStream_t stream) {
    const float* h   = (const float*)d_in[0];
    const int*   ei  = (const int*)d_in[1];    // [2, E]: row0 = src, row1 = tgt
    const float* ef  = (const float*)d_in[2];
    const float* W1  = (const float*)d_in[3];
    const float* b1  = (const float*)d_in[4];
    const float* W2  = (const float*)d_in[5];
    const float* b2  = (const float*)d_in[6];
    const float* Wih = (const float*)d_in[7];
    const float* Whh = (const float*)d_in[8];
    const float* bih = (const float*)d_in[9];
    const float* bhh = (const float*)d_in[10];
    float* out = (float*)d_out;

    // ws layout (floats). bf16 staging arrays OVERLAY the t region: they are
    // consumed by vmat_mfma, and t is written only afterwards (stream order).
    float* t    = (float*)d_ws;                        // 3,200,000 floats
    float* V    = t + 3200000;                         // 5000*4160
    float* m    = V + (size_t)N_NODES * RDIM;          // 320,000
    int*   cnt  = (int*)(m + 320000);                  // 5000
    int*   off  = cnt + N_NODES;                       // 5001
    int*   cur  = off + N_NODES + 1;                   // 5000
    int*   eperm= cur + N_NODES;                       // 50000
    int*   tgtp = eperm + N_EDGES;                     // 50000
    float* WihT = (float*)(tgtp + N_EDGES);            // 12288
    float* WhhT = WihT + 12288;                        // 12288
    __bf16* hhi = (__bf16*)d_ws;                       // 320000 (overlay)
    __bf16* hlo = hhi + 320000;                        // 320000
    __bf16* whi = hlo + 320000;                        // 266240
    __bf16* wlo = whi + 266240;                        // 266240 (< t's 12.8 MB)

    prep_kernel<<<3656, 256, 0, stream>>>(h, W2, b2, Wih, Whh,
                                          hhi, hlo, whi, wlo, WihT, WhhT, m, cnt);
    vmat_mfma<<<dim3(157, 5), 256, 0, stream>>>(hhi, hlo, whi, wlo, V);
    hist_kernel<<<(N_EDGES + 255) / 256, 256, 0, stream>>>(ei, cnt);
    scan_kernel<<<1, 1024, 0, stream>>>(cnt, off, cur);
    scatter_kernel<<<(N_EDGES + 255) / 256, 256, 0, stream>>>(ei, cur, eperm, tgtp);
    edge_mlp1_kernel<<<12500, 256, 0, stream>>>(eperm, ef, W1, b1, t);
    msg_kernel<<<2500, 256, 0, stream>>>(off, tgtp, t, V, m);
    gru_kernel<<<1250, 256, 0, stream>>>(m, h, WihT, WhhT, bih, bhh, out);
}